// Round 4
// baseline (421.604 us; speedup 1.0000x reference)
//
#include <hip/hip_runtime.h>
#include <hip/hip_bf16.h>

#define N_NODES 100000
#define N_EDGES 1600000
#define IN_F 128
#define OUT_F 32

#define NB 782        // ceil(100000 / 128) row buckets
#define NBP 784       // padded

typedef float v4f __attribute__((ext_vector_type(4)));

// ---------------- GEMM v2: support[N,32] = x[N,128] @ W[128,32] -------------
// 256 thr = 32 row-groups x 8 col-groups; each thread 4 rows x 4 cols.
// W staged in LDS (1 b128 per 4 k per thread, conflict-free broadcast);
// x read straight to registers (8-lane broadcast float4 loads, read once).
__global__ __launch_bounds__(256) void gcn_gemm_kernel(
    const float* __restrict__ x, const float* __restrict__ w,
    float* __restrict__ support) {
  __shared__ float wlds[IN_F][OUT_F];  // 16 KB
  const int t = threadIdx.x;
  const int tc = t & 7;        // col group
  const int tr = t >> 3;       // row group 0..31
  const int row0 = blockIdx.x * 128;
  const int c0 = tc * 4;
  const int r0 = row0 + tr * 4;

  for (int i = t; i < 1024; i += 256)
    ((float4*)wlds)[i] = ((const float4*)w)[i];
  __syncthreads();

  v4f a0 = 0.f, a1 = 0.f, a2 = 0.f, a3 = 0.f;
  const bool ok0 = (r0 + 0) < N_NODES, ok1 = (r0 + 1) < N_NODES,
             ok2 = (r0 + 2) < N_NODES, ok3 = (r0 + 3) < N_NODES;
  #pragma unroll 4
  for (int kb = 0; kb < IN_F; kb += 4) {
    v4f x0 = 0.f, x1 = 0.f, x2 = 0.f, x3 = 0.f;
    if (ok0) x0 = *(const v4f*)(x + (size_t)(r0 + 0) * IN_F + kb);
    if (ok1) x1 = *(const v4f*)(x + (size_t)(r0 + 1) * IN_F + kb);
    if (ok2) x2 = *(const v4f*)(x + (size_t)(r0 + 2) * IN_F + kb);
    if (ok3) x3 = *(const v4f*)(x + (size_t)(r0 + 3) * IN_F + kb);
    const v4f w0 = *(const v4f*)&wlds[kb + 0][c0];
    const v4f w1 = *(const v4f*)&wlds[kb + 1][c0];
    const v4f w2 = *(const v4f*)&wlds[kb + 2][c0];
    const v4f w3 = *(const v4f*)&wlds[kb + 3][c0];
    a0 += x0.x * w0; a1 += x1.x * w0; a2 += x2.x * w0; a3 += x3.x * w0;
    a0 += x0.y * w1; a1 += x1.y * w1; a2 += x2.y * w1; a3 += x3.y * w1;
    a0 += x0.z * w2; a1 += x1.z * w2; a2 += x2.z * w2; a3 += x3.z * w2;
    a0 += x0.w * w3; a1 += x1.w * w3; a2 += x2.w * w3; a3 += x3.w * w3;
  }
  if (ok0) *(v4f*)(support + (size_t)(r0 + 0) * OUT_F + c0) = a0;
  if (ok1) *(v4f*)(support + (size_t)(r0 + 1) * OUT_F + c0) = a1;
  if (ok2) *(v4f*)(support + (size_t)(r0 + 2) * OUT_F + c0) = a2;
  if (ok3) *(v4f*)(support + (size_t)(r0 + 3) * OUT_F + c0) = a3;
}

// ---------------- bucket histogram (by row>>7) ----------------
__global__ __launch_bounds__(256) void gcn_hist_kernel(
    const int* __restrict__ erow, int* __restrict__ hist_g) {
  __shared__ int h[NBP];
  const int t = threadIdx.x;
  for (int i = t; i < NBP; i += 256) h[i] = 0;
  __syncthreads();
  const int base = blockIdx.x * 4096;
  #pragma unroll
  for (int i = 0; i < 16; ++i) {
    const int e = base + i * 256 + t;
    if (e < N_EDGES) atomicAdd(&h[erow[e] >> 7], 1);
  }
  __syncthreads();
  for (int i = t; i < NBP; i += 256)
    if (h[i]) atomicAdd(&hist_g[i], h[i]);
}

// ---------------- scan 782 bucket counts -> bases, init cursors ----------------
__global__ __launch_bounds__(1024) void gcn_scan_kernel(
    const int* __restrict__ hist_g, int* __restrict__ bases,
    int* __restrict__ cursor) {
  __shared__ int s[1024];
  const int t = threadIdx.x;
  const int v = (t < NB) ? hist_g[t] : 0;
  s[t] = v;
  __syncthreads();
  for (int off = 1; off < 1024; off <<= 1) {
    const int add = (t >= off) ? s[t - off] : 0;
    __syncthreads();
    s[t] += add;
    __syncthreads();
  }
  if (t < NB) { const int b = s[t] - v; bases[t] = b; cursor[t] = b; }
  if (t == 0) bases[NB] = N_EDGES;
}

// ---------------- pass A: scatter edges into bucket-contiguous runs ---------
// 512 thr x 8 edges = 4096 edges/wg. LDS-sort by bucket, then coalesced flush.
__global__ __launch_bounds__(512) void gcn_bucket_kernel(
    const int* __restrict__ erow, const int* __restrict__ ecol,
    const float* __restrict__ eval, int* __restrict__ cursor,
    int2* __restrict__ bedges) {
  __shared__ int hist[1024];     // counts -> exclusive scan (in place), padded
  __shared__ int ps[512];
  __shared__ int gbase[NBP];
  __shared__ int cur[NBP];
  __shared__ int2 stage[4096];   // 32 KB
  __shared__ int dstg[4096];     // 16 KB
  const int t = threadIdx.x;
  const int wg0 = blockIdx.x * 4096;

  for (int i = t; i < 1024; i += 512) hist[i] = 0;
  for (int i = t; i < NBP; i += 512) cur[i] = 0;
  __syncthreads();

  int rowv[8], colv[8], bk[8];
  float valv[8];
  #pragma unroll
  for (int i = 0; i < 8; ++i) {
    const int e = wg0 + i * 512 + t;
    if (e < N_EDGES) {
      rowv[i] = erow[e]; colv[i] = ecol[e]; valv[i] = eval[e];
      bk[i] = rowv[i] >> 7;
      atomicAdd(&hist[bk[i]], 1);
    } else bk[i] = -1;
  }
  __syncthreads();

  // exclusive scan of hist[0..1023], two elements per thread, in place
  const int a0 = hist[2 * t], a1 = hist[2 * t + 1];
  ps[t] = a0 + a1;
  __syncthreads();
  for (int off = 1; off < 512; off <<= 1) {
    const int add = (t >= off) ? ps[t - off] : 0;
    __syncthreads();
    ps[t] += add;
    __syncthreads();
  }
  const int ex = t ? ps[t - 1] : 0;
  hist[2 * t] = ex;
  hist[2 * t + 1] = ex + a0;
  __syncthreads();

  // reserve global space per bucket
  for (int i = t; i < NB; i += 512) {
    const int cnt = hist[i + 1] - hist[i];
    gbase[i] = cnt ? atomicAdd(&cursor[i], cnt) : 0;
  }
  __syncthreads();

  // rank + stage (LDS pos and global slot share the same rank)
  #pragma unroll
  for (int i = 0; i < 8; ++i)
    if (bk[i] >= 0) {
      const int r = atomicAdd(&cur[bk[i]], 1);
      const int idx = hist[bk[i]] + r;
      stage[idx] = make_int2(colv[i] | ((rowv[i] & 127) << 17),
                             __float_as_int(valv[i]));
      dstg[idx] = gbase[bk[i]] + r;
    }
  __syncthreads();

  // coalesced-ish flush (consecutive LDS entries -> consecutive global slots)
  const int tot = min(4096, N_EDGES - wg0);
  for (int j = t; j < tot; j += 512) bedges[dstg[j]] = stage[j];
}

// ---------------- pass B: per-bucket LDS-tile aggregation -------------------
// One wg per bucket: accumulate val*support[col,:] into tile[128][32] via
// ds_add_f32 (bank = feature lane -> conflict-free), then one coalesced write.
__global__ __launch_bounds__(512) void gcn_aggregate_kernel(
    const float* __restrict__ support, const int* __restrict__ bases,
    const int2* __restrict__ bedges, const float* __restrict__ bias,
    float* __restrict__ out) {
  __shared__ float tile[128][32];  // 16 KB
  const int t = threadIdx.x;
  const int f = t & 31;
  const int g = t >> 5;            // 16 edge groups
  for (int i = t; i < 4096; i += 512) ((float*)tile)[i] = 0.f;
  const int b = blockIdx.x;
  const int s0 = bases[b], s1 = bases[b + 1];
  __syncthreads();

  const int len = s1 - s0;
  const int chunk = (len + 15) >> 4;
  int e = s0 + g * chunk;
  const int eend = min(e + chunk, s1);
  for (; e + 4 <= eend; e += 4) {
    const int2 e0 = bedges[e], e1 = bedges[e + 1];
    const int2 e2 = bedges[e + 2], e3 = bedges[e + 3];
    const float sv0 = support[(size_t)(e0.x & 0x1FFFF) * OUT_F + f];
    const float sv1 = support[(size_t)(e1.x & 0x1FFFF) * OUT_F + f];
    const float sv2 = support[(size_t)(e2.x & 0x1FFFF) * OUT_F + f];
    const float sv3 = support[(size_t)(e3.x & 0x1FFFF) * OUT_F + f];
    atomicAdd(&tile[e0.x >> 17][f], __int_as_float(e0.y) * sv0);
    atomicAdd(&tile[e1.x >> 17][f], __int_as_float(e1.y) * sv1);
    atomicAdd(&tile[e2.x >> 17][f], __int_as_float(e2.y) * sv2);
    atomicAdd(&tile[e3.x >> 17][f], __int_as_float(e3.y) * sv3);
  }
  for (; e < eend; ++e) {
    const int2 ed = bedges[e];
    atomicAdd(&tile[ed.x >> 17][f],
              __int_as_float(ed.y) * support[(size_t)(ed.x & 0x1FFFF) * OUT_F + f]);
  }
  __syncthreads();

  const int row0 = b << 7;
  const float bv = bias[f];
  for (int r = g; r < 128; r += 16) {
    const int row = row0 + r;
    if (row < N_NODES) out[(size_t)row * OUT_F + f] = tile[r][f] + bv;
  }
}

// ---------------- fallback (R1 proven path) ----------------
__global__ __launch_bounds__(256) void gcn_init_out_kernel(
    float* __restrict__ out, const float* __restrict__ bias) {
  const int i = blockIdx.x * 256 + threadIdx.x;
  if (i < N_NODES * OUT_F / 4)
    ((float4*)out)[i] = ((const float4*)bias)[i & 7];
}

__global__ __launch_bounds__(256) void gcn_scatter_kernel(
    const float* __restrict__ support, const int* __restrict__ erow,
    const int* __restrict__ ecol, const float* __restrict__ eval,
    float* __restrict__ out) {
  const long long idx = (long long)blockIdx.x * 256 + threadIdx.x;
  if (idx >= (long long)N_EDGES * OUT_F) return;
  const int e = (int)(idx >> 5);
  const int f = (int)(idx & 31);
  atomicAdd(&out[(size_t)erow[e] * OUT_F + f],
            eval[e] * support[(size_t)ecol[e] * OUT_F + f]);
}

extern "C" void kernel_launch(void* const* d_in, const int* in_sizes, int n_in,
                              void* d_out, int out_size, void* d_ws, size_t ws_size,
                              hipStream_t stream) {
  const float* x = (const float*)d_in[0];
  const int* erow = (const int*)d_in[1];
  const int* ecol = (const int*)d_in[2];
  const float* eval = (const float*)d_in[3];
  const float* w = (const float*)d_in[4];
  const float* bias = (const float*)d_in[5];
  float* out = (float*)d_out;
  char* ws = (char*)d_ws;

  // workspace layout
  const size_t SUP_OFF  = 0;                        // 12,800,000 B
  const size_t HG_OFF   = SUP_OFF + 12800000;       // 4096 B (bucket hist)
  const size_t BASE_OFF = HG_OFF + 4096;            // 4096 B (bases[NB+1])
  const size_t CUR_OFF  = BASE_OFF + 4096;          // 4096 B (cursors)
  const size_t BE_OFF   = CUR_OFF + 4096;           // 12,800,000 B (bucketed edges)
  const size_t NEEDED   = BE_OFF + 12800000;

  float* support = (float*)(ws + SUP_OFF);

  gcn_gemm_kernel<<<(N_NODES + 127) / 128, 256, 0, stream>>>(x, w, support);

  if (ws_size >= NEEDED) {
    int* hist_g = (int*)(ws + HG_OFF);
    int* bases  = (int*)(ws + BASE_OFF);
    int* cursor = (int*)(ws + CUR_OFF);
    int2* bedges = (int2*)(ws + BE_OFF);

    hipMemsetAsync(hist_g, 0, NBP * sizeof(int), stream);
    gcn_hist_kernel<<<(N_EDGES + 4095) / 4096, 256, 0, stream>>>(erow, hist_g);
    gcn_scan_kernel<<<1, 1024, 0, stream>>>(hist_g, bases, cursor);
    gcn_bucket_kernel<<<(N_EDGES + 4095) / 4096, 512, 0, stream>>>(
        erow, ecol, eval, cursor, bedges);
    gcn_aggregate_kernel<<<NB, 512, 0, stream>>>(support, bases, bedges, bias, out);
  } else {
    gcn_init_out_kernel<<<(N_NODES * OUT_F / 4 + 255) / 256, 256, 0, stream>>>(out, bias);
    const long long total = (long long)N_EDGES * OUT_F;
    gcn_scatter_kernel<<<(int)((total + 255) / 256), 256, 0, stream>>>(
        support, erow, ecol, eval, out);
  }
}

// Round 5
// 120.699 us; speedup vs baseline: 3.4930x; 3.4930x over previous
//
#include <hip/hip_runtime.h>
#include <hip/hip_bf16.h>

#define N_NODES 100000
#define N_EDGES 1600000
#define IN_F 128
#define OUT_F 32

#define NBK 391        // buckets of 256 rows: 391*256 = 100096
#define TILE_A 8192    // edges per pass-A workgroup
#define NWG_A 196      // ceil(1600000/8192)
#define CHUNK 4096     // pass-B sort/gather chunk

typedef float v4f __attribute__((ext_vector_type(4)));

__device__ inline unsigned short f2bf(float f) {
  unsigned u = __float_as_uint(f);
  return (unsigned short)((u + 0x7FFFu + ((u >> 16) & 1u)) >> 16);
}
__device__ inline float bf2f(unsigned short h) {
  return __uint_as_float(((unsigned)h) << 16);
}

// ---------------- GEMM: support_bf16[N,32] = x[N,128] @ W[128,32] -----------
__global__ __launch_bounds__(256) void gcn_gemm_kernel(
    const float* __restrict__ x, const float* __restrict__ w,
    unsigned short* __restrict__ sup) {
  __shared__ float wlds[IN_F][OUT_F];  // 16 KB
  const int t = threadIdx.x;
  const int tc = t & 7;
  const int tr = t >> 3;
  const int row0 = blockIdx.x * 128;
  const int c0 = tc * 4;
  const int r0 = row0 + tr * 4;

  for (int i = t; i < 1024; i += 256)
    ((float4*)wlds)[i] = ((const float4*)w)[i];
  __syncthreads();

  v4f a0 = 0.f, a1 = 0.f, a2 = 0.f, a3 = 0.f;
  const bool ok0 = (r0 + 0) < N_NODES, ok1 = (r0 + 1) < N_NODES,
             ok2 = (r0 + 2) < N_NODES, ok3 = (r0 + 3) < N_NODES;
  #pragma unroll 4
  for (int kb = 0; kb < IN_F; kb += 4) {
    v4f x0 = 0.f, x1 = 0.f, x2 = 0.f, x3 = 0.f;
    if (ok0) x0 = *(const v4f*)(x + (size_t)(r0 + 0) * IN_F + kb);
    if (ok1) x1 = *(const v4f*)(x + (size_t)(r0 + 1) * IN_F + kb);
    if (ok2) x2 = *(const v4f*)(x + (size_t)(r0 + 2) * IN_F + kb);
    if (ok3) x3 = *(const v4f*)(x + (size_t)(r0 + 3) * IN_F + kb);
    const v4f w0 = *(const v4f*)&wlds[kb + 0][c0];
    const v4f w1 = *(const v4f*)&wlds[kb + 1][c0];
    const v4f w2 = *(const v4f*)&wlds[kb + 2][c0];
    const v4f w3 = *(const v4f*)&wlds[kb + 3][c0];
    a0 += x0.x * w0; a1 += x1.x * w0; a2 += x2.x * w0; a3 += x3.x * w0;
    a0 += x0.y * w1; a1 += x1.y * w1; a2 += x2.y * w1; a3 += x3.y * w1;
    a0 += x0.z * w2; a1 += x1.z * w2; a2 += x2.z * w2; a3 += x3.z * w2;
    a0 += x0.w * w3; a1 += x1.w * w3; a2 += x2.w * w3; a3 += x3.w * w3;
  }
  ushort4 o0, o1, o2, o3;
  o0.x = f2bf(a0.x); o0.y = f2bf(a0.y); o0.z = f2bf(a0.z); o0.w = f2bf(a0.w);
  o1.x = f2bf(a1.x); o1.y = f2bf(a1.y); o1.z = f2bf(a1.z); o1.w = f2bf(a1.w);
  o2.x = f2bf(a2.x); o2.y = f2bf(a2.y); o2.z = f2bf(a2.z); o2.w = f2bf(a2.w);
  o3.x = f2bf(a3.x); o3.y = f2bf(a3.y); o3.z = f2bf(a3.z); o3.w = f2bf(a3.w);
  if (ok0) *(ushort4*)(sup + ((size_t)(r0 + 0) << 5) + c0) = o0;
  if (ok1) *(ushort4*)(sup + ((size_t)(r0 + 1) << 5) + c0) = o1;
  if (ok2) *(ushort4*)(sup + ((size_t)(r0 + 2) << 5) + c0) = o2;
  if (ok3) *(ushort4*)(sup + ((size_t)(r0 + 3) << 5) + c0) = o3;
}

// ---------------- pass A1: per-wg bucket hist -> padded global totals -------
__global__ __launch_bounds__(1024) void gcn_passA1_kernel(
    const int* __restrict__ erow, int* __restrict__ bpadtot) {
  __shared__ int h[NBK];
  const int t = threadIdx.x;
  for (int i = t; i < NBK; i += 1024) h[i] = 0;
  __syncthreads();
  const int base = blockIdx.x * TILE_A;
  #pragma unroll
  for (int i = 0; i < 8; ++i) {
    const int e = base + i * 1024 + t;
    if (e < N_EDGES) atomicAdd(&h[erow[e] >> 8], 1);
  }
  __syncthreads();
  for (int i = t; i < NBK; i += 1024) {
    const int c = h[i];
    if (c) atomicAdd(&bpadtot[i], (c + 7) & ~7);
  }
}

// ---------------- scan padded totals -> bases + cursors ----------------
__global__ __launch_bounds__(512) void gcn_scan_kernel(
    const int* __restrict__ bpadtot, int* __restrict__ bbase,
    int* __restrict__ bcursor) {
  __shared__ int s[512];
  const int t = threadIdx.x;
  const int v = (t < NBK) ? bpadtot[t] : 0;
  s[t] = v;
  __syncthreads();
  for (int off = 1; off < 512; off <<= 1) {
    const int a = (t >= off) ? s[t - off] : 0;
    __syncthreads();
    s[t] += a;
    __syncthreads();
  }
  if (t < NBK) { const int b = s[t] - v; bbase[t] = b; bcursor[t] = b; }
  if (t == 0) bbase[NBK] = s[NBK - 1];
}

// ---------------- pass A2: reserve sector-aligned chunks, scatter edges ----
// Each wg's per-bucket chunk is a multiple of 8 edges (64B) at a 64B-aligned
// base -> every written sector is wg-exclusive -> local-XCD L2 merges the
// partial writes. Gaps sentinel-filled with val=+0.0 (inert).
__global__ __launch_bounds__(1024) void gcn_passA2_kernel(
    const int* __restrict__ erow, const int* __restrict__ ecol,
    const float* __restrict__ eval, int* __restrict__ bcursor,
    int2* __restrict__ bedges) {
  __shared__ int h[NBK];
  __shared__ int gbase[NBK];
  __shared__ int lcur[NBK];
  const int t = threadIdx.x;
  for (int i = t; i < NBK; i += 1024) h[i] = 0;
  __syncthreads();
  const int base = blockIdx.x * TILE_A;
  #pragma unroll
  for (int i = 0; i < 8; ++i) {
    const int e = base + i * 1024 + t;
    if (e < N_EDGES) atomicAdd(&h[erow[e] >> 8], 1);
  }
  __syncthreads();
  for (int i = t; i < NBK; i += 1024) {
    const int c = h[i];
    gbase[i] = c ? atomicAdd(&bcursor[i], (c + 7) & ~7) : 0;
    lcur[i] = 0;
  }
  __syncthreads();
  #pragma unroll
  for (int i = 0; i < 8; ++i) {
    const int e = base + i * 1024 + t;
    if (e < N_EDGES) {
      const int r = erow[e];
      const int b = r >> 8;
      const int k = atomicAdd(&lcur[b], 1);
      bedges[gbase[b] + k] =
          make_int2(ecol[e] | ((r & 255) << 17), __float_as_int(eval[e]));
    }
  }
  __syncthreads();
  for (int i = t; i < NBK; i += 1024) {
    const int c = h[i];
    const int resv = (c + 7) & ~7;
    for (int j = c; j < resv; ++j) bedges[gbase[i] + j] = make_int2(0, 0);
  }
}

// ---------------- pass B: per-bucket chunked LDS sort + register gather -----
__global__ __launch_bounds__(1024) void gcn_gather_kernel(
    const unsigned short* __restrict__ sup, const int* __restrict__ bbase,
    const int2* __restrict__ bedges, const float* __restrict__ bias,
    float* __restrict__ out) {
  __shared__ int2 stage[CHUNK];   // 32 KB
  __shared__ int2 sorted[CHUNK];  // 32 KB
  __shared__ int hist[256];
  __shared__ int csr[257];
  __shared__ int cur[256];
  const int t = threadIdx.x;
  const int b = blockIdx.x;
  const int f = t & 31;
  const int g = t >> 5;  // 32 groups x 8 rows
  const int s0 = bbase[b], s1 = bbase[b + 1];
  const float bv = bias[f];
  float acc[8] = {0.f, 0.f, 0.f, 0.f, 0.f, 0.f, 0.f, 0.f};

  for (int c0 = s0; c0 < s1; c0 += CHUNK) {
    const int m = min(CHUNK, s1 - c0);
    // P1: load chunk + hist (skip inert val==+0 edges incl. sentinels)
    if (t < 256) hist[t] = 0;
    __syncthreads();
    for (int j = t; j < m; j += 1024) {
      const int2 ed = bedges[c0 + j];
      stage[j] = ed;
      if (ed.y != 0) atomicAdd(&hist[(ed.x >> 17) & 255], 1);
    }
    __syncthreads();
    // P2: exclusive scan of 256 counts
    if (t < 256) cur[t] = hist[t];
    __syncthreads();
    for (int off = 1; off < 256; off <<= 1) {
      int a = 0;
      if (t < 256 && t >= off) a = cur[t - off];
      __syncthreads();
      if (t < 256) cur[t] += a;
      __syncthreads();
    }
    if (t < 256) csr[t] = cur[t] - hist[t];
    if (t == 255) csr[256] = cur[255];
    __syncthreads();
    if (t < 256) cur[t] = csr[t];
    __syncthreads();
    // P3: scatter into row-sorted LDS order
    for (int j = t; j < m; j += 1024) {
      const int2 ed = stage[j];
      if (ed.y != 0) {
        const int lr = (ed.x >> 17) & 255;
        const int k = atomicAdd(&cur[lr], 1);
        sorted[k] = ed;
      }
    }
    __syncthreads();
    // P4: gather — group g owns rows g*8..g*8+7
    #pragma unroll
    for (int rr = 0; rr < 8; ++rr) {
      const int lr = g * 8 + rr;
      const int e1 = csr[lr + 1];
      int e = csr[lr];
      for (; e + 4 <= e1; e += 4) {
        const int2 q0 = sorted[e], q1 = sorted[e + 1];
        const int2 q2 = sorted[e + 2], q3 = sorted[e + 3];
        const float v0 = bf2f(sup[((size_t)(q0.x & 0x1FFFF) << 5) + f]);
        const float v1 = bf2f(sup[((size_t)(q1.x & 0x1FFFF) << 5) + f]);
        const float v2 = bf2f(sup[((size_t)(q2.x & 0x1FFFF) << 5) + f]);
        const float v3 = bf2f(sup[((size_t)(q3.x & 0x1FFFF) << 5) + f]);
        acc[rr] += __int_as_float(q0.y) * v0 + __int_as_float(q1.y) * v1 +
                   __int_as_float(q2.y) * v2 + __int_as_float(q3.y) * v3;
      }
      for (; e < e1; ++e) {
        const int2 q = sorted[e];
        acc[rr] += __int_as_float(q.y) *
                   bf2f(sup[((size_t)(q.x & 0x1FFFF) << 5) + f]);
      }
    }
    __syncthreads();  // protect stage/sorted/csr before next chunk
  }

  const int row0 = b << 8;
  #pragma unroll
  for (int rr = 0; rr < 8; ++rr) {
    const int row = row0 + g * 8 + rr;
    if (row < N_NODES) out[((size_t)row << 5) + f] = acc[rr] + bv;
  }
}

// ---------------- fallback: proven R1 atomic scatter (bf16 support) --------
__global__ __launch_bounds__(256) void gcn_init_out_kernel(
    float* __restrict__ out, const float* __restrict__ bias) {
  const int i = blockIdx.x * 256 + threadIdx.x;
  if (i < N_NODES * OUT_F / 4)
    ((float4*)out)[i] = ((const float4*)bias)[i & 7];
}

__global__ __launch_bounds__(256) void gcn_scatter_kernel(
    const unsigned short* __restrict__ sup, const int* __restrict__ erow,
    const int* __restrict__ ecol, const float* __restrict__ eval,
    float* __restrict__ out) {
  const long long idx = (long long)blockIdx.x * 256 + threadIdx.x;
  if (idx >= (long long)N_EDGES * OUT_F) return;
  const int e = (int)(idx >> 5);
  const int ff = (int)(idx & 31);
  atomicAdd(&out[((size_t)erow[e] << 5) + ff],
            eval[e] * bf2f(sup[((size_t)ecol[e] << 5) + ff]));
}

extern "C" void kernel_launch(void* const* d_in, const int* in_sizes, int n_in,
                              void* d_out, int out_size, void* d_ws, size_t ws_size,
                              hipStream_t stream) {
  const float* x = (const float*)d_in[0];
  const int* erow = (const int*)d_in[1];
  const int* ecol = (const int*)d_in[2];
  const float* eval = (const float*)d_in[3];
  const float* w = (const float*)d_in[4];
  const float* bias = (const float*)d_in[5];
  float* out = (float*)d_out;
  char* ws = (char*)d_ws;

  // workspace layout
  const size_t SUP_OFF = 0;                      // 6,400,000 B (bf16 support)
  const size_t BPT_OFF = SUP_OFF + 6400000;      // 4 KB (padded totals)
  const size_t BB_OFF  = BPT_OFF + 4096;         // 4 KB (bases, NBK+1)
  const size_t BC_OFF  = BB_OFF + 4096;          // 4 KB (cursors)
  const size_t BED_OFF = BC_OFF + 4096;          // 17,100,000 B (bucketed edges)
  const size_t NEEDED  = BED_OFF + 17100000;     // ~23.5 MB

  unsigned short* sup = (unsigned short*)(ws + SUP_OFF);

  gcn_gemm_kernel<<<(N_NODES + 127) / 128, 256, 0, stream>>>(x, w, sup);

  if (ws_size >= NEEDED) {
    int* bpadtot = (int*)(ws + BPT_OFF);
    int* bbase   = (int*)(ws + BB_OFF);
    int* bcursor = (int*)(ws + BC_OFF);
    int2* bedges = (int2*)(ws + BED_OFF);

    hipMemsetAsync(bpadtot, 0, NBK * sizeof(int), stream);
    gcn_passA1_kernel<<<NWG_A, 1024, 0, stream>>>(erow, bpadtot);
    gcn_scan_kernel<<<1, 512, 0, stream>>>(bpadtot, bbase, bcursor);
    gcn_passA2_kernel<<<NWG_A, 1024, 0, stream>>>(erow, ecol, eval, bcursor, bedges);
    gcn_gather_kernel<<<NBK, 1024, 0, stream>>>(sup, bbase, bedges, bias, out);
  } else if (ws_size >= 6400000) {
    gcn_init_out_kernel<<<(N_NODES * OUT_F / 4 + 255) / 256, 256, 0, stream>>>(out, bias);
    const long long total = (long long)N_EDGES * OUT_F;
    gcn_scatter_kernel<<<(int)((total + 255) / 256), 256, 0, stream>>>(
        sup, erow, ecol, eval, out);
  }
}

// Round 6
// 89.894 us; speedup vs baseline: 4.6900x; 1.3427x over previous
//
#include <hip/hip_runtime.h>
#include <hip/hip_bf16.h>

#define N_NODES 100000
#define N_EDGES 1600000
#define IN_F 128
#define OUT_F 32

#define NBK 782        // buckets of 128 rows: 782*128 = 100096
#define CAP 2816       // slots per bucket (mult of 8); mean fill ~2330
#define TILE_A 16384   // edges per pass-A wg
#define NWG_A 98       // ceil(1600000/16384)
#define NWG_G 782      // GEMM tiles of 128 rows
#define CHUNK 2048     // gather sort chunk
#define OVCAP 4096     // overflow list capacity

typedef float v4f __attribute__((ext_vector_type(4)));

__device__ inline unsigned short f2bf(float f) {
  unsigned u = __float_as_uint(f);
  return (unsigned short)((u + 0x7FFFu + ((u >> 16) & 1u)) >> 16);
}
__device__ inline float bf2f(unsigned short h) {
  return __uint_as_float(((unsigned)h) << 16);
}

// ---------------- fused: pass-A bucket scatter (blocks 0..97) +
//                  GEMM support_bf16 = x @ W (blocks 98..879) ----------------
__global__ __launch_bounds__(1024) void gcn_fused_kernel(
    const float* __restrict__ x, const float* __restrict__ w,
    unsigned short* __restrict__ sup, const int* __restrict__ erow,
    const int* __restrict__ ecol, const float* __restrict__ eval,
    int* __restrict__ cursor, int* __restrict__ ovcnt, int4* __restrict__ ov,
    int2* __restrict__ bedges) {
  __shared__ float wlds[IN_F][OUT_F];          // 16 KB (GEMM blocks)
  __shared__ int h[NBK];                       // 9.4 KB total (A blocks)
  __shared__ int gbase[NBK];
  __shared__ int lcur[NBK];
  const int t = threadIdx.x;

  if (blockIdx.x < NWG_A) {
    // ---- pass A: sector-exclusive padded bucket scatter ----
    for (int i = t; i < NBK; i += 1024) h[i] = 0;
    __syncthreads();
    const int base = blockIdx.x * TILE_A;
    int rowv[16];
    #pragma unroll
    for (int i = 0; i < 16; ++i) {
      const int e = base + i * 1024 + t;
      rowv[i] = (e < N_EDGES) ? erow[e] : -1;
      if (rowv[i] >= 0) atomicAdd(&h[rowv[i] >> 7], 1);
    }
    __syncthreads();
    if (t < NBK) {
      const int c = h[t];
      gbase[t] = c ? atomicAdd(&cursor[t], (c + 7) & ~7) : 0;
      lcur[t] = 0;
    }
    __syncthreads();
    #pragma unroll
    for (int i = 0; i < 16; ++i) {
      const int e = base + i * 1024 + t;
      if (rowv[i] >= 0) {
        const int b = rowv[i] >> 7;
        const int lr = rowv[i] & 127;
        const int k = atomicAdd(&lcur[b], 1);
        const int pos = gbase[b] + k;
        const int2 pk = make_int2(ecol[e] | (lr << 17), __float_as_int(eval[e]));
        if (pos < CAP) {
          bedges[(size_t)b * CAP + pos] = pk;
        } else {
          const int o = atomicAdd(ovcnt, 1);
          if (o < OVCAP) ov[o] = make_int4(b, pk.x, pk.y, 0);
        }
      }
    }
    __syncthreads();
    if (t < NBK) {
      const int c = h[t];
      const int resv = (c + 7) & ~7;
      for (int j = c; j < resv; ++j) {
        const int pos = gbase[t] + j;
        if (pos < CAP) bedges[(size_t)t * CAP + pos] = make_int2(0, 0);
      }
    }
  } else {
    // ---- GEMM tile: 128 rows, thread = 1 row x 4 cols ----
    const int gb = blockIdx.x - NWG_A;
    const int row0 = gb << 7;
    ((float4*)wlds)[t] = ((const float4*)w)[t];  // 1024 float4 = all of W
    __syncthreads();
    const int tr = t >> 3;
    const int c0 = (t & 7) * 4;
    const int row = row0 + tr;
    const int rl = (row < N_NODES) ? row : (N_NODES - 1);
    const float* xr = x + (size_t)rl * IN_F;
    v4f acc = 0.f;
    #pragma unroll 4
    for (int kb = 0; kb < IN_F; kb += 4) {
      const v4f xv = *(const v4f*)(xr + kb);
      const v4f w0 = *(const v4f*)&wlds[kb + 0][c0];
      const v4f w1 = *(const v4f*)&wlds[kb + 1][c0];
      const v4f w2 = *(const v4f*)&wlds[kb + 2][c0];
      const v4f w3 = *(const v4f*)&wlds[kb + 3][c0];
      acc += xv.x * w0;
      acc += xv.y * w1;
      acc += xv.z * w2;
      acc += xv.w * w3;
    }
    if (row < N_NODES) {
      ushort4 o;
      o.x = f2bf(acc.x); o.y = f2bf(acc.y); o.z = f2bf(acc.z); o.w = f2bf(acc.w);
      *(ushort4*)(sup + ((size_t)row << 5) + c0) = o;
    }
  }
}

// ---------------- gather: per-bucket chunked LDS sort + register gather -----
__global__ __launch_bounds__(1024) void gcn_gather_kernel(
    const unsigned short* __restrict__ sup, const int* __restrict__ cursor,
    const int2* __restrict__ bedges, const int* __restrict__ ovcnt,
    const int4* __restrict__ ov, const float* __restrict__ bias,
    float* __restrict__ out) {
  __shared__ int2 stage[CHUNK];    // 16 KB
  __shared__ int2 sorted[CHUNK];   // 16 KB
  __shared__ int hist[128];
  __shared__ int csr[129];
  __shared__ int cur[128];
  const int t = threadIdx.x;
  const int b = blockIdx.x;
  const int f = t & 31;
  const int g = t >> 5;            // 32 groups x 4 rows
  const int ext = min(cursor[b], CAP);
  const float bv = bias[f];
  const size_t bb = (size_t)b * CAP;
  float acc[4] = {0.f, 0.f, 0.f, 0.f};

  for (int c0 = 0; c0 < ext; c0 += CHUNK) {
    const int m = min(CHUNK, ext - c0);
    if (t < 128) hist[t] = 0;
    __syncthreads();
    for (int j = t; j < m; j += 1024) {
      const int2 ed = bedges[bb + c0 + j];
      stage[j] = ed;
      if (ed.y != 0) atomicAdd(&hist[(ed.x >> 17) & 127], 1);
    }
    __syncthreads();
    if (t < 128) cur[t] = hist[t];
    __syncthreads();
    for (int off = 1; off < 128; off <<= 1) {
      int a = 0;
      if (t < 128 && t >= off) a = cur[t - off];
      __syncthreads();
      if (t < 128) cur[t] += a;
      __syncthreads();
    }
    if (t < 128) csr[t] = cur[t] - hist[t];
    if (t == 127) csr[128] = cur[127];
    __syncthreads();
    if (t < 128) cur[t] = csr[t];
    __syncthreads();
    for (int j = t; j < m; j += 1024) {
      const int2 ed = stage[j];
      if (ed.y != 0) {
        const int k = atomicAdd(&cur[(ed.x >> 17) & 127], 1);
        sorted[k] = ed;
      }
    }
    __syncthreads();
    #pragma unroll
    for (int rr = 0; rr < 4; ++rr) {
      const int lr = g * 4 + rr;
      const int e1 = csr[lr + 1];
      int e = csr[lr];
      for (; e + 4 <= e1; e += 4) {
        const int2 q0 = sorted[e], q1 = sorted[e + 1];
        const int2 q2 = sorted[e + 2], q3 = sorted[e + 3];
        const float v0 = bf2f(sup[((size_t)(q0.x & 0x1FFFF) << 5) + f]);
        const float v1 = bf2f(sup[((size_t)(q1.x & 0x1FFFF) << 5) + f]);
        const float v2 = bf2f(sup[((size_t)(q2.x & 0x1FFFF) << 5) + f]);
        const float v3 = bf2f(sup[((size_t)(q3.x & 0x1FFFF) << 5) + f]);
        acc[rr] += __int_as_float(q0.y) * v0 + __int_as_float(q1.y) * v1 +
                   __int_as_float(q2.y) * v2 + __int_as_float(q3.y) * v3;
      }
      for (; e < e1; ++e) {
        const int2 q = sorted[e];
        acc[rr] += __int_as_float(q.y) *
                   bf2f(sup[((size_t)(q.x & 0x1FFFF) << 5) + f]);
      }
    }
    __syncthreads();
  }

  // overflow fold (expected 0 entries; race-free: only bucket b applies its own)
  const int on = min(*ovcnt, OVCAP);
  for (int i = 0; i < on; ++i) {
    const int4 q = ov[i];
    if (q.x == b) {
      const int lr = (q.y >> 17) & 127;
      if ((lr >> 2) == g)
        acc[lr & 3] += __int_as_float(q.z) *
                       bf2f(sup[((size_t)(q.y & 0x1FFFF) << 5) + f]);
    }
  }

  const int row0 = b << 7;
  #pragma unroll
  for (int rr = 0; rr < 4; ++rr) {
    const int row = row0 + g * 4 + rr;
    if (row < N_NODES) out[((size_t)row << 5) + f] = acc[rr] + bv;
  }
}

// ---------------- fallback: proven atomic scatter (bf16 support) ------------
__global__ __launch_bounds__(256) void gcn_gemm_fb_kernel(
    const float* __restrict__ x, const float* __restrict__ w,
    unsigned short* __restrict__ sup) {
  __shared__ float wlds[IN_F][OUT_F];
  const int t = threadIdx.x;
  for (int i = t; i < 1024; i += 256)
    ((float4*)wlds)[i] = ((const float4*)w)[i];
  __syncthreads();
  const int tr = t >> 3;
  const int c0 = (t & 7) * 4;
  const int row = blockIdx.x * 32 + tr;
  if (row >= N_NODES) return;
  const float* xr = x + (size_t)row * IN_F;
  v4f acc = 0.f;
  #pragma unroll 4
  for (int kb = 0; kb < IN_F; kb += 4) {
    const v4f xv = *(const v4f*)(xr + kb);
    acc += xv.x * *(const v4f*)&wlds[kb + 0][c0];
    acc += xv.y * *(const v4f*)&wlds[kb + 1][c0];
    acc += xv.z * *(const v4f*)&wlds[kb + 2][c0];
    acc += xv.w * *(const v4f*)&wlds[kb + 3][c0];
  }
  ushort4 o;
  o.x = f2bf(acc.x); o.y = f2bf(acc.y); o.z = f2bf(acc.z); o.w = f2bf(acc.w);
  *(ushort4*)(sup + ((size_t)row << 5) + c0) = o;
}

__global__ __launch_bounds__(256) void gcn_init_out_kernel(
    float* __restrict__ out, const float* __restrict__ bias) {
  const int i = blockIdx.x * 256 + threadIdx.x;
  if (i < N_NODES * OUT_F / 4)
    ((float4*)out)[i] = ((const float4*)bias)[i & 7];
}

__global__ __launch_bounds__(256) void gcn_scatter_kernel(
    const unsigned short* __restrict__ sup, const int* __restrict__ erow,
    const int* __restrict__ ecol, const float* __restrict__ eval,
    float* __restrict__ out) {
  const long long idx = (long long)blockIdx.x * 256 + threadIdx.x;
  if (idx >= (long long)N_EDGES * OUT_F) return;
  const int e = (int)(idx >> 5);
  const int ff = (int)(idx & 31);
  atomicAdd(&out[((size_t)erow[e] << 5) + ff],
            eval[e] * bf2f(sup[((size_t)ecol[e] << 5) + ff]));
}

extern "C" void kernel_launch(void* const* d_in, const int* in_sizes, int n_in,
                              void* d_out, int out_size, void* d_ws, size_t ws_size,
                              hipStream_t stream) {
  const float* x = (const float*)d_in[0];
  const int* erow = (const int*)d_in[1];
  const int* ecol = (const int*)d_in[2];
  const float* eval = (const float*)d_in[3];
  const float* w = (const float*)d_in[4];
  const float* bias = (const float*)d_in[5];
  float* out = (float*)d_out;
  char* ws = (char*)d_ws;

  // workspace layout (64B-aligned chunks)
  const size_t SUP_OFF = 0;                          // 6,400,000 B (bf16 support)
  const size_t CUR_OFF = SUP_OFF + 6400000;          // 782*4 = 3128 B cursors
  const size_t OVC_OFF = CUR_OFF + 3128;             // 4 B overflow count
  const size_t OV_OFF  = CUR_OFF + 3200;             // 4096*16 = 65,536 B
  const size_t BED_OFF = OV_OFF + 65536;             // 782*2816*8 = 17,618,944 B
  const size_t NEEDED  = BED_OFF + (size_t)NBK * CAP * 8;  // ~24.1 MB

  unsigned short* sup = (unsigned short*)(ws + SUP_OFF);

  if (ws_size >= NEEDED) {
    int* cursor = (int*)(ws + CUR_OFF);
    int* ovcnt  = (int*)(ws + OVC_OFF);
    int4* ov    = (int4*)(ws + OV_OFF);
    int2* bedges = (int2*)(ws + BED_OFF);

    // zero cursors + overflow count (3132 B, contiguous)
    hipMemsetAsync(cursor, 0, 3132, stream);
    gcn_fused_kernel<<<NWG_A + NWG_G, 1024, 0, stream>>>(
        x, w, sup, erow, ecol, eval, cursor, ovcnt, ov, bedges);
    gcn_gather_kernel<<<NBK, 1024, 0, stream>>>(
        sup, cursor, bedges, ovcnt, ov, bias, out);
  } else if (ws_size >= 6400000) {
    gcn_gemm_fb_kernel<<<(N_NODES + 31) / 32, 256, 0, stream>>>(x, w, sup);
    gcn_init_out_kernel<<<(N_NODES * OUT_F / 4 + 255) / 256, 256, 0, stream>>>(out, bias);
    const long long total = (long long)N_EDGES * OUT_F;
    gcn_scatter_kernel<<<(int)((total + 255) / 256), 256, 0, stream>>>(
        sup, erow, ecol, eval, out);
  }
}

// Round 7
// 84.101 us; speedup vs baseline: 5.0130x; 1.0689x over previous
//
#include <hip/hip_runtime.h>
#include <hip/hip_bf16.h>

#define N_NODES 100000
#define N_EDGES 1600000
#define IN_F 128
#define OUT_F 32

#define NBK 782        // buckets of 128 rows: 782*128 = 100096
#define CAP 2816       // slots per bucket (mult of 8); mean fill ~2330
#define TILE_A 16384   // edges per pass-A wg
#define NWG_A 98       // ceil(1600000/16384)
#define NWG_M 391      // MFMA gemm blocks: 16 waves x 16 rows = 256 rows each
#define CHUNK 2048     // gather sort chunk
#define OVCAP 4096     // overflow list capacity

typedef float v4f __attribute__((ext_vector_type(4)));
typedef short bf16x8 __attribute__((ext_vector_type(8)));
typedef float f32x4 __attribute__((ext_vector_type(4)));

__device__ inline unsigned short f2bf(float f) {
  unsigned u = __float_as_uint(f);
  return (unsigned short)((u + 0x7FFFu + ((u >> 16) & 1u)) >> 16);
}
__device__ inline float bf2f(unsigned short h) {
  return __uint_as_float(((unsigned)h) << 16);
}
__device__ inline unsigned pk2(float lo, float hi) {
  return (unsigned)f2bf(lo) | ((unsigned)f2bf(hi) << 16);
}

// ---------------- fused: pass-A bucket scatter (blocks 0..97) +
//                  MFMA GEMM support_bf16 = x @ W (blocks 98..488) -----------
__global__ __launch_bounds__(1024) void gcn_fused_kernel(
    const float* __restrict__ x, const float* __restrict__ w,
    unsigned short* __restrict__ sup, const int* __restrict__ erow,
    const int* __restrict__ ecol, const float* __restrict__ eval,
    int* __restrict__ cursor, int* __restrict__ ovcnt, int4* __restrict__ ov,
    int2* __restrict__ bedges) {
  __shared__ int h[NBK];
  __shared__ int gbase[NBK];
  __shared__ int lcur[NBK];
  const int t = threadIdx.x;

  if (blockIdx.x < NWG_A) {
    // ---- pass A: sector-exclusive padded bucket scatter (proven R6) ----
    for (int i = t; i < NBK; i += 1024) h[i] = 0;
    __syncthreads();
    const int base = blockIdx.x * TILE_A;
    int rowv[16];
    #pragma unroll
    for (int i = 0; i < 16; ++i) {
      const int e = base + i * 1024 + t;
      rowv[i] = (e < N_EDGES) ? erow[e] : -1;
      if (rowv[i] >= 0) atomicAdd(&h[rowv[i] >> 7], 1);
    }
    __syncthreads();
    if (t < NBK) {
      const int c = h[t];
      gbase[t] = c ? atomicAdd(&cursor[t], (c + 7) & ~7) : 0;
      lcur[t] = 0;
    }
    __syncthreads();
    #pragma unroll
    for (int i = 0; i < 16; ++i) {
      const int e = base + i * 1024 + t;
      if (rowv[i] >= 0) {
        const int b = rowv[i] >> 7;
        const int lr = rowv[i] & 127;
        const int k = atomicAdd(&lcur[b], 1);
        const int pos = gbase[b] + k;
        const int2 pk = make_int2(ecol[e] | (lr << 17), __float_as_int(eval[e]));
        if (pos < CAP) {
          bedges[(size_t)b * CAP + pos] = pk;
        } else {
          const int o = atomicAdd(ovcnt, 1);
          if (o < OVCAP) ov[o] = make_int4(b, pk.x, pk.y, 0);
        }
      }
    }
    __syncthreads();
    if (t < NBK) {
      const int c = h[t];
      const int resv = (c + 7) & ~7;
      for (int j = c; j < resv; ++j) {
        const int pos = gbase[t] + j;
        if (pos < CAP) bedges[(size_t)t * CAP + pos] = make_int2(0, 0);
      }
    }
  } else {
    // ---- MFMA GEMM: wave = one 16-row tile, 2 n-tiles x 4 k-steps ----
    const int wid = t >> 6;
    const int lane = t & 63;
    const int tile = (blockIdx.x - NWG_A) * 16 + wid;   // 0..6255
    const int row0 = tile << 4;
    const int lr = lane & 15;   // A row / B,D col index
    const int lg = lane >> 4;   // 0..3 (k-group / D row-group)

    // B fragments from W (L1/L2-hot): B[k][c], k=kk*32+lg*8+j, c=nt*16+lr
    bf16x8 bfrag[2][4];
    #pragma unroll
    for (int nt = 0; nt < 2; ++nt) {
      #pragma unroll
      for (int kk = 0; kk < 4; ++kk) {
        const int c = nt * 16 + lr;
        const int k0 = kk * 32 + lg * 8;
        union { unsigned u[4]; bf16x8 v; } bf;
        #pragma unroll
        for (int d = 0; d < 4; ++d)
          bf.u[d] = pk2(w[(k0 + 2 * d) * OUT_F + c],
                        w[(k0 + 2 * d + 1) * OUT_F + c]);
        bfrag[nt][kk] = bf.v;
      }
    }

    const int row = row0 + lr;
    const int rl = (row < N_NODES) ? row : (N_NODES - 1);
    const float* xr = x + (size_t)rl * IN_F;
    f32x4 acc0 = {0.f, 0.f, 0.f, 0.f};
    f32x4 acc1 = {0.f, 0.f, 0.f, 0.f};
    #pragma unroll
    for (int kk = 0; kk < 4; ++kk) {
      const v4f p0 = *(const v4f*)(xr + kk * 32 + lg * 8);
      const v4f p1 = *(const v4f*)(xr + kk * 32 + lg * 8 + 4);
      union { unsigned u[4]; bf16x8 v; } af;
      af.u[0] = pk2(p0.x, p0.y);
      af.u[1] = pk2(p0.z, p0.w);
      af.u[2] = pk2(p1.x, p1.y);
      af.u[3] = pk2(p1.z, p1.w);
      acc0 = __builtin_amdgcn_mfma_f32_16x16x32_bf16(af.v, bfrag[0][kk], acc0, 0, 0, 0);
      acc1 = __builtin_amdgcn_mfma_f32_16x16x32_bf16(af.v, bfrag[1][kk], acc1, 0, 0, 0);
    }
    // D layout: col = lane&15, row = lg*4 + i   (m89-verified)
    #pragma unroll
    for (int i = 0; i < 4; ++i) {
      const int r = row0 + lg * 4 + i;
      if (r < N_NODES) {
        sup[((size_t)r << 5) + lr] = f2bf(acc0[i]);
        sup[((size_t)r << 5) + 16 + lr] = f2bf(acc1[i]);
      }
    }
  }
}

// ---------------- gather: per-bucket chunked LDS sort + register gather -----
__global__ __launch_bounds__(1024) void gcn_gather_kernel(
    const unsigned short* __restrict__ sup, const int* __restrict__ cursor,
    const int2* __restrict__ bedges, const int* __restrict__ ovcnt,
    const int4* __restrict__ ov, const float* __restrict__ bias,
    float* __restrict__ out) {
  __shared__ int2 stage[CHUNK];    // 16 KB
  __shared__ int2 sorted[CHUNK];   // 16 KB
  __shared__ int hist[128];
  __shared__ int csr[129];
  __shared__ int cur[128];
  const int t = threadIdx.x;
  const int b = blockIdx.x;
  const int f = t & 31;
  const int g = t >> 5;            // 32 groups x 4 rows
  const int ext = min(cursor[b], CAP);
  const float bv = bias[f];
  const size_t bb = (size_t)b * CAP;
  float acc[4] = {0.f, 0.f, 0.f, 0.f};

  for (int c0 = 0; c0 < ext; c0 += CHUNK) {
    const int m = min(CHUNK, ext - c0);
    if (t < 128) hist[t] = 0;
    __syncthreads();
    for (int j = t; j < m; j += 1024) {
      const int2 ed = bedges[bb + c0 + j];
      stage[j] = ed;
      if (ed.y != 0) atomicAdd(&hist[(ed.x >> 17) & 127], 1);
    }
    __syncthreads();
    if (t < 128) cur[t] = hist[t];
    __syncthreads();
    for (int off = 1; off < 128; off <<= 1) {
      int a = 0;
      if (t < 128 && t >= off) a = cur[t - off];
      __syncthreads();
      if (t < 128) cur[t] += a;
      __syncthreads();
    }
    if (t < 128) csr[t] = cur[t] - hist[t];
    if (t == 127) csr[128] = cur[127];
    __syncthreads();
    if (t < 128) cur[t] = csr[t];
    __syncthreads();
    for (int j = t; j < m; j += 1024) {
      const int2 ed = stage[j];
      if (ed.y != 0) {
        const int k = atomicAdd(&cur[(ed.x >> 17) & 127], 1);
        sorted[k] = ed;
      }
    }
    __syncthreads();
    #pragma unroll
    for (int rr = 0; rr < 4; ++rr) {
      const int lr = g * 4 + rr;
      const int e1 = csr[lr + 1];
      int e = csr[lr];
      for (; e + 4 <= e1; e += 4) {
        const int2 q0 = sorted[e], q1 = sorted[e + 1];
        const int2 q2 = sorted[e + 2], q3 = sorted[e + 3];
        const float v0 = bf2f(sup[((size_t)(q0.x & 0x1FFFF) << 5) + f]);
        const float v1 = bf2f(sup[((size_t)(q1.x & 0x1FFFF) << 5) + f]);
        const float v2 = bf2f(sup[((size_t)(q2.x & 0x1FFFF) << 5) + f]);
        const float v3 = bf2f(sup[((size_t)(q3.x & 0x1FFFF) << 5) + f]);
        acc[rr] += __int_as_float(q0.y) * v0 + __int_as_float(q1.y) * v1 +
                   __int_as_float(q2.y) * v2 + __int_as_float(q3.y) * v3;
      }
      for (; e < e1; ++e) {
        const int2 q = sorted[e];
        acc[rr] += __int_as_float(q.y) *
                   bf2f(sup[((size_t)(q.x & 0x1FFFF) << 5) + f]);
      }
    }
    __syncthreads();
  }

  const int on = min(*ovcnt, OVCAP);
  for (int i = 0; i < on; ++i) {
    const int4 q = ov[i];
    if (q.x == b) {
      const int lr = (q.y >> 17) & 127;
      if ((lr >> 2) == g)
        acc[lr & 3] += __int_as_float(q.z) *
                       bf2f(sup[((size_t)(q.y & 0x1FFFF) << 5) + f]);
    }
  }

  const int row0 = b << 7;
  #pragma unroll
  for (int rr = 0; rr < 4; ++rr) {
    const int row = row0 + g * 4 + rr;
    if (row < N_NODES) out[((size_t)row << 5) + f] = acc[rr] + bv;
  }
}

// ---------------- fallback: proven atomic scatter (bf16 support) ------------
__global__ __launch_bounds__(256) void gcn_gemm_fb_kernel(
    const float* __restrict__ x, const float* __restrict__ w,
    unsigned short* __restrict__ sup) {
  __shared__ float wlds[IN_F][OUT_F];
  const int t = threadIdx.x;
  for (int i = t; i < 1024; i += 256)
    ((float4*)wlds)[i] = ((const float4*)w)[i];
  __syncthreads();
  const int tr = t >> 3;
  const int c0 = (t & 7) * 4;
  const int row = blockIdx.x * 32 + tr;
  if (row >= N_NODES) return;
  const float* xr = x + (size_t)row * IN_F;
  v4f acc = 0.f;
  #pragma unroll 4
  for (int kb = 0; kb < IN_F; kb += 4) {
    const v4f xv = *(const v4f*)(xr + kb);
    acc += xv.x * *(const v4f*)&wlds[kb + 0][c0];
    acc += xv.y * *(const v4f*)&wlds[kb + 1][c0];
    acc += xv.z * *(const v4f*)&wlds[kb + 2][c0];
    acc += xv.w * *(const v4f*)&wlds[kb + 3][c0];
  }
  ushort4 o;
  o.x = f2bf(acc.x); o.y = f2bf(acc.y); o.z = f2bf(acc.z); o.w = f2bf(acc.w);
  *(ushort4*)(sup + ((size_t)row << 5) + c0) = o;
}

__global__ __launch_bounds__(256) void gcn_init_out_kernel(
    float* __restrict__ out, const float* __restrict__ bias) {
  const int i = blockIdx.x * 256 + threadIdx.x;
  if (i < N_NODES * OUT_F / 4)
    ((float4*)out)[i] = ((const float4*)bias)[i & 7];
}

__global__ __launch_bounds__(256) void gcn_scatter_kernel(
    const unsigned short* __restrict__ sup, const int* __restrict__ erow,
    const int* __restrict__ ecol, const float* __restrict__ eval,
    float* __restrict__ out) {
  const long long idx = (long long)blockIdx.x * 256 + threadIdx.x;
  if (idx >= (long long)N_EDGES * OUT_F) return;
  const int e = (int)(idx >> 5);
  const int ff = (int)(idx & 31);
  atomicAdd(&out[((size_t)erow[e] << 5) + ff],
            eval[e] * bf2f(sup[((size_t)ecol[e] << 5) + ff]));
}

extern "C" void kernel_launch(void* const* d_in, const int* in_sizes, int n_in,
                              void* d_out, int out_size, void* d_ws, size_t ws_size,
                              hipStream_t stream) {
  const float* x = (const float*)d_in[0];
  const int* erow = (const int*)d_in[1];
  const int* ecol = (const int*)d_in[2];
  const float* eval = (const float*)d_in[3];
  const float* w = (const float*)d_in[4];
  const float* bias = (const float*)d_in[5];
  float* out = (float*)d_out;
  char* ws = (char*)d_ws;

  // workspace layout
  const size_t SUP_OFF = 0;                          // 6,400,000 B (bf16 support)
  const size_t CUR_OFF = SUP_OFF + 6400000;          // 782*4 = 3128 B cursors
  const size_t OVC_OFF = CUR_OFF + 3128;             // 4 B overflow count
  const size_t OV_OFF  = CUR_OFF + 3200;             // 4096*16 = 65,536 B
  const size_t BED_OFF = OV_OFF + 65536;             // 782*2816*8 = 17,618,944 B
  const size_t NEEDED  = BED_OFF + (size_t)NBK * CAP * 8;  // ~24.1 MB

  unsigned short* sup = (unsigned short*)(ws + SUP_OFF);

  if (ws_size >= NEEDED) {
    int* cursor = (int*)(ws + CUR_OFF);
    int* ovcnt  = (int*)(ws + OVC_OFF);
    int4* ov    = (int4*)(ws + OV_OFF);
    int2* bedges = (int2*)(ws + BED_OFF);

    hipMemsetAsync(cursor, 0, 3132, stream);
    gcn_fused_kernel<<<NWG_A + NWG_M, 1024, 0, stream>>>(
        x, w, sup, erow, ecol, eval, cursor, ovcnt, ov, bedges);
    gcn_gather_kernel<<<NBK, 1024, 0, stream>>>(
        sup, cursor, bedges, ovcnt, ov, bias, out);
  } else if (ws_size >= 6400000) {
    gcn_gemm_fb_kernel<<<(N_NODES + 31) / 32, 256, 0, stream>>>(x, w, sup);
    gcn_init_out_kernel<<<(N_NODES * OUT_F / 4 + 255) / 256, 256, 0, stream>>>(out, bias);
    const long long total = (long long)N_EDGES * OUT_F;
    gcn_scatter_kernel<<<(int)((total + 255) / 256), 256, 0, stream>>>(
        sup, erow, ecol, eval, out);
  }
}